// Round 18
// baseline (110.430 us; speedup 1.0000x reference)
//
#include <hip/hip_runtime.h>

typedef _Float16 f16;
typedef _Float16 f16x2 __attribute__((ext_vector_type(2)));
typedef _Float16 f16x4 __attribute__((ext_vector_type(4)));
typedef _Float16 f16x8 __attribute__((ext_vector_type(8)));
typedef float    f32x4 __attribute__((ext_vector_type(4)));

#define KW 31
#define R  15
#define NP 32
#define HH 512
#define WW 512
#define NB 4

#define TW 32            // output tile width (px)
#define TH 32            // output tile height
#define EXT_X 62         // data cols 0..61; cols 62..71 zero
#define SX 72            // tile row stride (f16); 36 dw ≡ 4 mod 32 -> A-frag b128 2-way (free)
#define EXT_Y 63         // 62 data rows + 1 zero row
#define GB 32            // weight table base: copy0 idx = GB + tap
#define C0_L 96          // copy0 length (f16), idx 0..95
#define C1_O 96          // copy1 offset within plane (even f16 -> dword-aligned)
#define PL_S 198         // per-plane stride (f16) = 99 dwords ≡ 3 mod 32:
                         // plane index maps BIJECTIVELY onto banks (3·pm mod 32).
                         // R17's even stride (98 dw) confined wy reads to even banks
                         // -> >=4-way pileup = the remaining 4.4e6 conflict cycles.

// LDS: tile 27216 + gTh2 12672 + pl8 1024 = 40912 -> 40960 alloc -> 4 blocks/CU (cap)
__global__ __launch_bounds__(256, 1) void defocus_kernel(
    const float* __restrict__ sharp, const float* __restrict__ coc_map,
    float* __restrict__ out)
{
    __shared__ __align__(16) f16 tile[3][EXT_Y][SX];
    __shared__ __align__(16) f16 gTh2[NP][PL_S];   // [copy0 96 | copy1 96 | pad 6]
    __shared__ unsigned char pl8[TH][TW];

    const int tid = threadIdx.x;
    const int bx = blockIdx.x, by = blockIdx.y, bb = blockIdx.z;

    // ---- phase 1: per-plane Gaussian weights; copy0 natural, copy1 = copy0 shifted 1 ----
    if (tid < NP) {
        const int p = tid;
        for (int i = 0; i < PL_S; ++i) gTh2[p][i] = (f16)0.0f;
        const double step = 50.0 / 31.0;
        const float pv = (p == 31) ? 50.0f : (float)((double)p * step);
        if (pv < 0.5f) {
            gTh2[p][GB + R] = (f16)1.0f;
        } else {
            const double coc   = (double)pv;
            const double sigma = coc / 2.355;
            int k = (int)(2.0 * coc + 1.0);
            if ((k & 1) == 0) k += 1;
            if (k > KW) k = KW;
            const int half = k >> 1;
            float s = 0.0f;
            for (int j = 0; j < k; ++j) {
                double c = (double)(j - half);
                s += (float)exp(-(c * c) / (2.0 * sigma * sigma));
            }
            for (int j = 0; j < k; ++j) {
                double c = (double)(j - half);
                const float w = (float)exp(-(c * c) / (2.0 * sigma * sigma)) / s;
                gTh2[p][GB + (R - half + j)] = (f16)w;
            }
        }
        for (int i = 0; i < C0_L - 1; ++i) gTh2[p][C1_O + i] = gTh2[p][i + 1];
        gTh2[p][C1_O + C0_L - 1] = (f16)0.0f;
    }
    __syncthreads();

    // ---- phase 2a: per-pixel plane selection; boundaries in registers (exact ref math) ----
    {
        const int row = tid >> 3;
        const int x4  = (tid & 7) * 4;
        const float4 c4 = *(const float4*)&coc_map[((size_t)bb * HH + by * TH + row) * WW + bx * TW + x4];
        const float cv[4] = {c4.x, c4.y, c4.z, c4.w};
        int pp[4] = {0, 0, 0, 0};
        const double step = 50.0 / 31.0;
        #pragma unroll 1
        for (int k = 0; k < KW; ++k) {
            const float pa = (float)((double)k * step);
            const float pb = (k == 30) ? 50.0f : (float)((double)(k + 1) * step);
            const float b = (pa + pb) * 0.5f;
            pp[0] += (cv[0] > b) ? 1 : 0;
            pp[1] += (cv[1] > b) ? 1 : 0;
            pp[2] += (cv[2] > b) ? 1 : 0;
            pp[3] += (cv[3] > b) ? 1 : 0;
        }
        *(uchar4*)&pl8[row][x4] = make_uchar4((unsigned char)pp[0], (unsigned char)pp[1],
                                              (unsigned char)pp[2], (unsigned char)pp[3]);
    }

    // ---- phase 2b: stage tile (+halo) as f16, zero all padding ----
    for (int idx = tid; idx < 3 * EXT_Y * (SX / 2); idx += 256) {
        const int dw = idx % (SX / 2);
        const int rr = (idx / (SX / 2)) % EXT_Y;
        const int ch = idx / ((SX / 2) * EXT_Y);
        const int gy  = by * TH - R + rr;
        const int gxa = bx * TW - R + 2 * dw;
        float va = 0.0f, vb = 0.0f;
        if (rr < 62 && (unsigned)gy < HH) {
            const float* src = &sharp[(((size_t)bb * 3 + ch) * HH + gy) * WW];
            if (2 * dw     < EXT_X && (unsigned)gxa       < WW) va = src[gxa];
            if (2 * dw + 1 < EXT_X && (unsigned)(gxa + 1) < WW) vb = src[gxa + 1];
        }
        f16x2 h; h.x = (f16)va; h.y = (f16)vb;
        *(f16x2*)&tile[ch][rr][2 * dw] = h;
    }
    __syncthreads();

    // ---- phase 3: merged-segment GEMM; vectorized parity-table weight loads ----
    // Output px (seg s, lane c) = tile col 16s+c+15; window f16 idx o = GB+k-c-16s.
    const int lid = tid & 63, wv = tid >> 6;
    const int c = lid & 15, q = lid >> 4;
    const int cp = c & 1;                       // parity copy (o parity == c parity)
    const int dwb = (GB + 8 * q - c) >> 1;      // seg0 chunk0 start dword within copy

    union U { f16x2 h2[4]; f16x8 h8; };
    union W { f16x2 h2[2]; f16x4 h4; };

    #pragma unroll 2
    for (int r = wv; r < TH; r += 4) {          // 32 tasks: one per row
        const int pm0 = pl8[r][c];
        const int pm1 = pl8[r][16 + c];
        const f16* tab0 = &gTh2[pm0][cp ? C1_O : 0];
        const f16* tab1 = &gTh2[pm1][cp ? C1_O : 0];

        // B-frag vectors: f16s [o..o+7] == copy-cp dwords [o>>1 .. (o>>1)+3]
        U b00, b01, b10, b11;                   // [seg][chunk]
        #pragma unroll
        for (int n = 0; n < 4; ++n) {
            b00.h2[n] = *(const f16x2*)&tab0[2 * (dwb + n)];        // seg0 chunk0
            b01.h2[n] = *(const f16x2*)&tab0[2 * (dwb + 16 + n)];   // seg0 chunk1
            b10.h2[n] = *(const f16x2*)&tab1[2 * (dwb - 8 + n)];    // seg1 chunk0
            b11.h2[n] = *(const f16x2*)&tab1[2 * (dwb + 8 + n)];    // seg1 chunk1
        }

        // y-weights from copy0 (f16x2 pairs: plane base may be odd-dword; banks 3*pm spread)
        W wy0A, wy0B, wy1A, wy1B;
        wy0A.h2[0] = *(const f16x2*)&gTh2[pm0][GB + 4 * q];
        wy0A.h2[1] = *(const f16x2*)&gTh2[pm0][GB + 4 * q + 2];
        wy0B.h2[0] = *(const f16x2*)&gTh2[pm0][GB + 16 + 4 * q];
        wy0B.h2[1] = *(const f16x2*)&gTh2[pm0][GB + 16 + 4 * q + 2];
        wy1A.h2[0] = *(const f16x2*)&gTh2[pm1][GB + 4 * q];
        wy1A.h2[1] = *(const f16x2*)&gTh2[pm1][GB + 4 * q + 2];
        wy1B.h2[0] = *(const f16x2*)&gTh2[pm1][GB + 16 + 4 * q];
        wy1B.h2[1] = *(const f16x2*)&gTh2[pm1][GB + 16 + 4 * q + 2];

        float o[2][3];
        #pragma unroll
        for (int ch = 0; ch < 3; ++ch) {
            float s0 = 0.0f, s1 = 0.0f;
            #pragma unroll
            for (int nt = 0; nt < 2; ++nt) {
                // shared data A-frag: A[m=c (dy row)][k=8q+j(+32)] = tile[r+16nt+c][k]
                const f16* ap = &tile[ch][r + nt * 16 + c][q * 8];
                const f16x8 a0 = *(const f16x8*)ap;
                const f16x8 a1 = *(const f16x8*)(ap + 32);
                f32x4 acc0 = {0.f, 0.f, 0.f, 0.f};
                acc0 = __builtin_amdgcn_mfma_f32_16x16x32_f16(a0, b00.h8, acc0, 0, 0, 0);
                acc0 = __builtin_amdgcn_mfma_f32_16x16x32_f16(a1, b01.h8, acc0, 0, 0, 0);
                f32x4 acc1 = {0.f, 0.f, 0.f, 0.f};
                acc1 = __builtin_amdgcn_mfma_f32_16x16x32_f16(a0, b10.h8, acc1, 0, 0, 0);
                acc1 = __builtin_amdgcn_mfma_f32_16x16x32_f16(a1, b11.h8, acc1, 0, 0, 0);
                const f16x4 w0 = nt ? wy0B.h4 : wy0A.h4;
                const f16x4 w1 = nt ? wy1B.h4 : wy1A.h4;
                #pragma unroll
                for (int i = 0; i < 4; ++i) {
                    s0 = fmaf((float)w0[i], acc0[i], s0);
                    s1 = fmaf((float)w1[i], acc1[i], s1);
                }
            }
            o[0][ch] = s0;
            o[1][ch] = s1;
        }

        // cross-quad sum: lanes {c, c+16, c+32, c+48} hold the 4 dy-partials
        #pragma unroll
        for (int sg = 0; sg < 2; ++sg)
            #pragma unroll
            for (int ch = 0; ch < 3; ++ch) {
                o[sg][ch] += __shfl_xor(o[sg][ch], 16, 64);
                o[sg][ch] += __shfl_xor(o[sg][ch], 32, 64);
            }

        if (q == 0) {
            const int oy = by * TH + r;
            #pragma unroll
            for (int sg = 0; sg < 2; ++sg) {
                const int ox = bx * TW + 16 * sg + c;
                #pragma unroll
                for (int ch = 0; ch < 3; ++ch)
                    out[(((size_t)bb * 3 + ch) * HH + oy) * WW + ox] = o[sg][ch];
            }
        }
    }
}

extern "C" void kernel_launch(void* const* d_in, const int* in_sizes, int n_in,
                              void* d_out, int out_size, void* d_ws, size_t ws_size,
                              hipStream_t stream) {
    const float* sharp = (const float*)d_in[0];
    const float* coc   = (const float*)d_in[1];
    float* outp        = (float*)d_out;
    dim3 grid(WW / TW, HH / TH, NB);
    defocus_kernel<<<grid, dim3(256), 0, stream>>>(sharp, coc, outp);
}

// Round 19
// 105.353 us; speedup vs baseline: 1.0482x; 1.0482x over previous
//
#include <hip/hip_runtime.h>

typedef _Float16 f16;
typedef _Float16 f16x2 __attribute__((ext_vector_type(2)));
typedef _Float16 f16x4 __attribute__((ext_vector_type(4)));
typedef _Float16 f16x8 __attribute__((ext_vector_type(8)));
typedef float    f32x16 __attribute__((ext_vector_type(16)));

#define KW 31
#define R  15
#define NP 32
#define HH 512
#define WW 512
#define NB 4

#define TW 32            // output tile width (px)
#define TH 32            // output tile height
#define EXT_X 62         // data cols 0..61; cols 62..71 zero
#define SX 72            // tile row stride (f16)
#define EXT_Y 63         // 62 data rows + 1 zero row
#define GB 32            // weight table base: idx = GB + tap
#define GT_S 98          // per-copy row length (f16), R17-proven layout

// LDS: tile 27216 + gTh2 12544 + pl8 1024 + bnd 124 = 40908 -> 4 blocks/CU (cap 40960)
__global__ __launch_bounds__(256, 1) void defocus_kernel(
    const float* __restrict__ sharp, const float* __restrict__ coc_map,
    float* __restrict__ out)
{
    __shared__ __align__(16) f16 tile[3][EXT_Y][SX];
    __shared__ __align__(16) f16 gTh2[NP][2][GT_S];    // [plane][parity copy][idx]
    __shared__ unsigned char pl8[TH][TW];
    __shared__ float bnd[KW];

    const int tid = threadIdx.x;
    const int bx = blockIdx.x, by = blockIdx.y, bb = blockIdx.z;

    // ---- phase 1: per-plane Gaussian weights; copy0 natural, copy1 = copy0 shifted 1 ----
    if (tid < NP) {
        const int p = tid;
        for (int i = 0; i < GT_S; ++i) gTh2[p][0][i] = (f16)0.0f;
        const double step = 50.0 / 31.0;
        const float pv = (p == 31) ? 50.0f : (float)((double)p * step);
        if (pv < 0.5f) {
            gTh2[p][0][GB + R] = (f16)1.0f;
        } else {
            const double coc   = (double)pv;
            const double sigma = coc / 2.355;
            int k = (int)(2.0 * coc + 1.0);
            if ((k & 1) == 0) k += 1;
            if (k > KW) k = KW;
            const int half = k >> 1;
            float s = 0.0f;
            for (int j = 0; j < k; ++j) {
                double c = (double)(j - half);
                s += (float)exp(-(c * c) / (2.0 * sigma * sigma));
            }
            for (int j = 0; j < k; ++j) {
                double c = (double)(j - half);
                const float w = (float)exp(-(c * c) / (2.0 * sigma * sigma)) / s;
                gTh2[p][0][GB + (R - half + j)] = (f16)w;
            }
        }
        for (int i = 0; i < GT_S - 1; ++i) gTh2[p][1][i] = gTh2[p][0][i + 1];
        gTh2[p][1][GT_S - 1] = (f16)0.0f;
    }
    if (tid < KW) {
        const double step = 50.0 / 31.0;
        const float pa = (float)((double)tid * step);
        const float pb = (tid == 30) ? 50.0f : (float)((double)(tid + 1) * step);
        bnd[tid] = (pa + pb) * 0.5f;
    }
    __syncthreads();

    // ---- phase 2a: per-pixel plane selection (exact: count coc > bnd[k]) ----
    {
        const int row = tid >> 3;
        const int x4  = (tid & 7) * 4;
        const float4 c4 = *(const float4*)&coc_map[((size_t)bb * HH + by * TH + row) * WW + bx * TW + x4];
        const float cv[4] = {c4.x, c4.y, c4.z, c4.w};
        int pp[4] = {0, 0, 0, 0};
        #pragma unroll
        for (int k = 0; k < KW; ++k) {
            const float b = bnd[k];
            pp[0] += (cv[0] > b) ? 1 : 0;
            pp[1] += (cv[1] > b) ? 1 : 0;
            pp[2] += (cv[2] > b) ? 1 : 0;
            pp[3] += (cv[3] > b) ? 1 : 0;
        }
        *(uchar4*)&pl8[row][x4] = make_uchar4((unsigned char)pp[0], (unsigned char)pp[1],
                                              (unsigned char)pp[2], (unsigned char)pp[3]);
    }

    // ---- phase 2b: stage tile (+halo) as f16, zero all padding ----
    for (int idx = tid; idx < 3 * EXT_Y * (SX / 2); idx += 256) {
        const int dw = idx % (SX / 2);
        const int rr = (idx / (SX / 2)) % EXT_Y;
        const int ch = idx / ((SX / 2) * EXT_Y);
        const int gy  = by * TH - R + rr;
        const int gxa = bx * TW - R + 2 * dw;
        float va = 0.0f, vb = 0.0f;
        if (rr < 62 && (unsigned)gy < HH) {
            const float* src = &sharp[(((size_t)bb * 3 + ch) * HH + gy) * WW];
            if (2 * dw     < EXT_X && (unsigned)gxa       < WW) va = src[gxa];
            if (2 * dw + 1 < EXT_X && (unsigned)(gxa + 1) < WW) vb = src[gxa + 1];
        }
        f16x2 h; h.x = (f16)va; h.y = (f16)vb;
        *(f16x2*)&tile[ch][rr][2 * dw] = h;
    }
    __syncthreads();

    // ---- phase 3: one 32x32 GEMM (K=64) per (row, channel) ----
    // S[dy][px] = sum_k tile[r+dy][k] * g_{plane(px)}[k - px]   (tap = k-px, zero-padded)
    // A: m=lane&31 (dy), k=(lane>>5)*8+j (+16kc). C/D: col=lane&31 (px),
    // row=(reg&3)+8(reg>>2)+4(lane>>5) (dy). Partials split only across h=lane>>5.
    const int lid = tid & 63, wv = tid >> 6;
    const int c32 = lid & 31, h = lid >> 5;
    const int cp = c32 & 1;                       // parity copy (window parity == px parity)
    const int dwb0 = (GB + 8 * h - c32) >> 1;     // chunk-0 start dword within copy; in [0,20]

    union U8 { f16x2 h2[4]; f16x8 h8; };

    #pragma unroll 2
    for (int r = wv; r < TH; r += 4) {            // 32 tasks: one per row
        const int pm = pl8[r][c32];
        const f16* tab = &gTh2[pm][cp][0];

        // B-frags: chunk kc covers k=16kc+8h+j; f16 idx o = GB + k - c32
        U8 bf[4];
        #pragma unroll
        for (int kc = 0; kc < 4; ++kc)
            #pragma unroll
            for (int n = 0; n < 4; ++n)
                bf[kc].h2[n] = *(const f16x2*)&tab[2 * (dwb0 + 8 * kc + n)];

        // y-weights: dy = 8a + 4h + b  -> 4 aligned f16x4 (b64) reads
        f16x4 wy[4];
        #pragma unroll
        for (int a = 0; a < 4; ++a)
            wy[a] = *(const f16x4*)&gTh2[pm][0][GB + 8 * a + 4 * h];

        float o[3];
        #pragma unroll
        for (int ch = 0; ch < 3; ++ch) {
            const f16* ap = &tile[ch][r + c32][8 * h];
            f32x16 acc;
            #pragma unroll
            for (int i = 0; i < 16; ++i) acc[i] = 0.0f;
            acc = __builtin_amdgcn_mfma_f32_32x32x16_f16(*(const f16x8*)(ap     ), bf[0].h8, acc, 0, 0, 0);
            acc = __builtin_amdgcn_mfma_f32_32x32x16_f16(*(const f16x8*)(ap + 16), bf[1].h8, acc, 0, 0, 0);
            acc = __builtin_amdgcn_mfma_f32_32x32x16_f16(*(const f16x8*)(ap + 32), bf[2].h8, acc, 0, 0, 0);
            acc = __builtin_amdgcn_mfma_f32_32x32x16_f16(*(const f16x8*)(ap + 48), bf[3].h8, acc, 0, 0, 0);
            float s = 0.0f;
            #pragma unroll
            for (int a = 0; a < 4; ++a)
                #pragma unroll
                for (int b = 0; b < 4; ++b)
                    s = fmaf((float)wy[a][b], acc[4 * a + b], s);
            o[ch] = s;
        }

        // other dy-half lives at lane ^ 32
        #pragma unroll
        for (int ch = 0; ch < 3; ++ch) o[ch] += __shfl_xor(o[ch], 32, 64);

        if (h == 0) {
            const int oy = by * TH + r;
            const int ox = bx * TW + c32;
            #pragma unroll
            for (int ch = 0; ch < 3; ++ch)
                out[(((size_t)bb * 3 + ch) * HH + oy) * WW + ox] = o[ch];
        }
    }
}

extern "C" void kernel_launch(void* const* d_in, const int* in_sizes, int n_in,
                              void* d_out, int out_size, void* d_ws, size_t ws_size,
                              hipStream_t stream) {
    const float* sharp = (const float*)d_in[0];
    const float* coc   = (const float*)d_in[1];
    float* outp        = (float*)d_out;
    dim3 grid(WW / TW, HH / TH, NB);
    defocus_kernel<<<grid, dim3(256), 0, stream>>>(sharp, coc, outp);
}

// Round 20
// 104.108 us; speedup vs baseline: 1.0607x; 1.0120x over previous
//
#include <hip/hip_runtime.h>

typedef _Float16 f16;
typedef _Float16 f16x2 __attribute__((ext_vector_type(2)));
typedef _Float16 f16x4 __attribute__((ext_vector_type(4)));
typedef _Float16 f16x8 __attribute__((ext_vector_type(8)));
typedef float    f32x16 __attribute__((ext_vector_type(16)));

#define KW 31
#define R  15
#define NP 32
#define HH 512
#define WW 512
#define NB 4

#define TW 32            // output tile width (px)
#define TH 32            // output tile height
#define EXT_X 62         // data cols 0..61; cols 62..71 zero
#define SX 72            // tile row stride (f16)
#define EXT_Y 63         // 62 data rows + 1 zero row
#define GB 32            // weight table base: idx = GB + tap
#define GT_S 98          // per-copy row length (f16), R17-proven layout

// LDS: tile 27216 + gTh2 12544 + pl8 1024 + bnd 124 = 40908 -> 4 blocks/CU (cap 40960)
__global__ __launch_bounds__(256, 1) void defocus_kernel(
    const float* __restrict__ sharp, const float* __restrict__ coc_map,
    float* __restrict__ out)
{
    __shared__ __align__(16) f16 tile[3][EXT_Y][SX];
    __shared__ __align__(16) f16 gTh2[NP][2][GT_S];    // [plane][parity copy][idx]
    __shared__ unsigned char pl8[TH][TW];
    __shared__ float bnd[KW];

    const int tid = threadIdx.x;
    const int bx = blockIdx.x, by = blockIdx.y, bb = blockIdx.z;

    // ---- phase 1: per-plane Gaussian weights; copy0 natural, copy1 = copy0 shifted 1 ----
    if (tid < NP) {
        const int p = tid;
        for (int i = 0; i < GT_S; ++i) gTh2[p][0][i] = (f16)0.0f;
        const double step = 50.0 / 31.0;
        const float pv = (p == 31) ? 50.0f : (float)((double)p * step);
        if (pv < 0.5f) {
            gTh2[p][0][GB + R] = (f16)1.0f;
        } else {
            const double coc   = (double)pv;
            const double sigma = coc / 2.355;
            int k = (int)(2.0 * coc + 1.0);
            if ((k & 1) == 0) k += 1;
            if (k > KW) k = KW;
            const int half = k >> 1;
            float s = 0.0f;
            for (int j = 0; j < k; ++j) {
                double c = (double)(j - half);
                s += (float)exp(-(c * c) / (2.0 * sigma * sigma));
            }
            for (int j = 0; j < k; ++j) {
                double c = (double)(j - half);
                const float w = (float)exp(-(c * c) / (2.0 * sigma * sigma)) / s;
                gTh2[p][0][GB + (R - half + j)] = (f16)w;
            }
        }
        for (int i = 0; i < GT_S - 1; ++i) gTh2[p][1][i] = gTh2[p][0][i + 1];
        gTh2[p][1][GT_S - 1] = (f16)0.0f;
    }
    if (tid < KW) {
        const double step = 50.0 / 31.0;
        const float pa = (float)((double)tid * step);
        const float pb = (tid == 30) ? 50.0f : (float)((double)(tid + 1) * step);
        bnd[tid] = (pa + pb) * 0.5f;
    }
    __syncthreads();

    // ---- phase 2a: per-pixel plane selection (exact: count coc > bnd[k]) ----
    {
        const int row = tid >> 3;
        const int x4  = (tid & 7) * 4;
        const float4 c4 = *(const float4*)&coc_map[((size_t)bb * HH + by * TH + row) * WW + bx * TW + x4];
        const float cv[4] = {c4.x, c4.y, c4.z, c4.w};
        int pp[4] = {0, 0, 0, 0};
        #pragma unroll
        for (int k = 0; k < KW; ++k) {
            const float b = bnd[k];
            pp[0] += (cv[0] > b) ? 1 : 0;
            pp[1] += (cv[1] > b) ? 1 : 0;
            pp[2] += (cv[2] > b) ? 1 : 0;
            pp[3] += (cv[3] > b) ? 1 : 0;
        }
        *(uchar4*)&pl8[row][x4] = make_uchar4((unsigned char)pp[0], (unsigned char)pp[1],
                                              (unsigned char)pp[2], (unsigned char)pp[3]);
    }

    // ---- phase 2b: stage tile (+halo) as f16, zero all padding ----
    for (int idx = tid; idx < 3 * EXT_Y * (SX / 2); idx += 256) {
        const int dw = idx % (SX / 2);
        const int rr = (idx / (SX / 2)) % EXT_Y;
        const int ch = idx / ((SX / 2) * EXT_Y);
        const int gy  = by * TH - R + rr;
        const int gxa = bx * TW - R + 2 * dw;
        float va = 0.0f, vb = 0.0f;
        if (rr < 62 && (unsigned)gy < HH) {
            const float* src = &sharp[(((size_t)bb * 3 + ch) * HH + gy) * WW];
            if (2 * dw + 1 < EXT_X && (unsigned)gxa < WW && (unsigned)(gxa + 1) < WW) {
                const float2 v2 = *(const float2*)&src[gxa];   // interior: one dwordx2
                va = v2.x; vb = v2.y;
            } else {
                if (2 * dw     < EXT_X && (unsigned)gxa       < WW) va = src[gxa];
                if (2 * dw + 1 < EXT_X && (unsigned)(gxa + 1) < WW) vb = src[gxa + 1];
            }
        }
        f16x2 h; h.x = (f16)va; h.y = (f16)vb;
        *(f16x2*)&tile[ch][rr][2 * dw] = h;
    }
    __syncthreads();

    // ---- phase 3: one 32x32 GEMM (K=64) per (row, channel) ----
    // S[dy][px] = sum_k tile[r+dy][k] * g_{plane(px)}[k - px]   (tap = k-px, zero-padded)
    // A: m=lane&31 (dy), k=(lane>>5)*8+j (+16kc). C/D: col=lane&31 (px),
    // row=(reg&3)+8(reg>>2)+4(lane>>5) (dy). Partials split only across h=lane>>5.
    const int lid = tid & 63, wv = tid >> 6;
    const int c32 = lid & 31, h = lid >> 5;
    const int cp = c32 & 1;                       // parity copy (window parity == px parity)
    const int dwb0 = (GB + 8 * h - c32) >> 1;     // chunk-0 start dword within copy; in [0,20]

    union U8 { f16x2 h2[4]; f16x8 h8; };

    // unroll 4: four independent task chains in flight per wave (VGPR budget 256
    // at (256,1); R19's VGPR=52 showed the latency chains were starved of ILP)
    #pragma unroll 4
    for (int r = wv; r < TH; r += 4) {            // 32 tasks: one per row
        const int pm = pl8[r][c32];
        const f16* tab = &gTh2[pm][cp][0];

        // B-frags: chunk kc covers k=16kc+8h+j; f16 idx o = GB + k - c32
        U8 bf[4];
        #pragma unroll
        for (int kc = 0; kc < 4; ++kc)
            #pragma unroll
            for (int n = 0; n < 4; ++n)
                bf[kc].h2[n] = *(const f16x2*)&tab[2 * (dwb0 + 8 * kc + n)];

        // y-weights: dy = 8a + 4h + b  -> 4 aligned f16x4 (b64) reads
        f16x4 wy[4];
        #pragma unroll
        for (int a = 0; a < 4; ++a)
            wy[a] = *(const f16x4*)&gTh2[pm][0][GB + 8 * a + 4 * h];

        float o[3];
        #pragma unroll
        for (int ch = 0; ch < 3; ++ch) {
            const f16* ap = &tile[ch][r + c32][8 * h];
            f32x16 acc;
            #pragma unroll
            for (int i = 0; i < 16; ++i) acc[i] = 0.0f;
            acc = __builtin_amdgcn_mfma_f32_32x32x16_f16(*(const f16x8*)(ap     ), bf[0].h8, acc, 0, 0, 0);
            acc = __builtin_amdgcn_mfma_f32_32x32x16_f16(*(const f16x8*)(ap + 16), bf[1].h8, acc, 0, 0, 0);
            acc = __builtin_amdgcn_mfma_f32_32x32x16_f16(*(const f16x8*)(ap + 32), bf[2].h8, acc, 0, 0, 0);
            acc = __builtin_amdgcn_mfma_f32_32x32x16_f16(*(const f16x8*)(ap + 48), bf[3].h8, acc, 0, 0, 0);
            float s = 0.0f;
            #pragma unroll
            for (int a = 0; a < 4; ++a)
                #pragma unroll
                for (int b = 0; b < 4; ++b)
                    s = fmaf((float)wy[a][b], acc[4 * a + b], s);
            o[ch] = s;
        }

        // other dy-half lives at lane ^ 32
        #pragma unroll
        for (int ch = 0; ch < 3; ++ch) o[ch] += __shfl_xor(o[ch], 32, 64);

        if (h == 0) {
            const int oy = by * TH + r;
            const int ox = bx * TW + c32;
            #pragma unroll
            for (int ch = 0; ch < 3; ++ch)
                out[(((size_t)bb * 3 + ch) * HH + oy) * WW + ox] = o[ch];
        }
    }
}

extern "C" void kernel_launch(void* const* d_in, const int* in_sizes, int n_in,
                              void* d_out, int out_size, void* d_ws, size_t ws_size,
                              hipStream_t stream) {
    const float* sharp = (const float*)d_in[0];
    const float* coc   = (const float*)d_in[1];
    float* outp        = (float*)d_out;
    dim3 grid(WW / TW, HH / TH, NB);
    defocus_kernel<<<grid, dim3(256), 0, stream>>>(sharp, coc, outp);
}

// Round 21
// 96.905 us; speedup vs baseline: 1.1396x; 1.0743x over previous
//
#include <hip/hip_runtime.h>

typedef _Float16 f16;
typedef _Float16 f16x2 __attribute__((ext_vector_type(2)));
typedef _Float16 f16x4 __attribute__((ext_vector_type(4)));
typedef _Float16 f16x8 __attribute__((ext_vector_type(8)));
typedef float    f32x16 __attribute__((ext_vector_type(16)));

#define KW 31
#define R  15
#define NP 32
#define HH 512
#define WW 512
#define NB 4

#define TW 32            // output tile width (px)
#define TH 32            // output tile height
#define EXT_X 62         // data cols 0..61; cols 62..71 zero
#define SX 72            // tile row stride (f16)
#define EXT_Y 63         // 62 data rows + 1 zero row
#define GB 32            // weight table base: idx = GB + tap
#define GT_S 98          // per-copy row length (f16), R17-proven layout

// LDS: tile 27216 + gTh2 12544 + pl8 1024 + bnd 124 = 40908 -> 4 blocks/CU (cap 40960)
__global__ __launch_bounds__(256, 1) void defocus_kernel(
    const float* __restrict__ sharp, const float* __restrict__ coc_map,
    float* __restrict__ out)
{
    __shared__ __align__(16) f16 tile[3][EXT_Y][SX];
    __shared__ __align__(16) f16 gTh2[NP][2][GT_S];    // [plane][parity copy][idx]
    __shared__ unsigned char pl8[TH][TW];
    __shared__ float bnd[KW];

    const int tid = threadIdx.x;
    const int bx = blockIdx.x, by = blockIdx.y, bb = blockIdx.z;

    // ---- phase 1a: zero weight table (256-thread parallel) + exact boundaries ----
    for (int i = tid; i < NP * GT_S; i += 256)     // NP*2*GT_S f16 = NP*GT_S f16x2
        ((f16x2*)gTh2)[i] = (f16x2){(f16)0.0f, (f16)0.0f};
    if (tid < KW) {                                 // boundaries stay f64-exact (bucket edges)
        const double step = 50.0 / 31.0;
        const float pa = (float)((double)tid * step);
        const float pb = (tid == 30) ? 50.0f : (float)((double)(tid + 1) * step);
        bnd[tid] = (pa + pb) * 0.5f;
    }
    __syncthreads();

    // ---- phase 1b: copy0 weights, 8 threads per plane, f32 exp ----
    // (weight VALUES are f16-quantized -> f32 exp is lossless at tolerance;
    //  k and pv derivation stay f64 to match reference integer boundaries)
    {
        const int p = tid >> 3, sub = tid & 7;
        const double step = 50.0 / 31.0;
        const float pv = (p == 31) ? 50.0f : (float)((double)p * step);
        if (pv < 0.5f) {
            if (sub == 0) gTh2[p][0][GB + R] = (f16)1.0f;
        } else {
            const double coc = (double)pv;
            int k = (int)(2.0 * coc + 1.0);
            if ((k & 1) == 0) k += 1;
            if (k > KW) k = KW;
            const int half = k >> 1;
            const float sigma = (float)(coc / 2.355);
            const float inv2s2 = 1.0f / (2.0f * sigma * sigma);
            float w[4]; float s = 0.0f;
            #pragma unroll
            for (int m = 0; m < 4; ++m) {
                const int t = sub + 8 * m;
                float val = 0.0f;
                if (t < k) {
                    const float cc = (float)(t - half);
                    val = __expf(-(cc * cc) * inv2s2);
                }
                w[m] = val; s += val;
            }
            s += __shfl_xor(s, 1, 64);              // 8-lane group sum (contiguous lanes)
            s += __shfl_xor(s, 2, 64);
            s += __shfl_xor(s, 4, 64);
            const float inv = 1.0f / s;
            #pragma unroll
            for (int m = 0; m < 4; ++m) {
                const int t = sub + 8 * m;
                if (t < k) gTh2[p][0][GB + (R - half + t)] = (f16)(w[m] * inv);
            }
        }
    }
    __syncthreads();

    // ---- phase 1c: copy1 = copy0 shifted 1 (256-thread parallel) ----
    for (int idx = tid; idx < NP * GT_S; idx += 256) {
        const int p = idx / GT_S, i = idx - p * GT_S;
        gTh2[p][1][i] = (i < GT_S - 1) ? gTh2[p][0][i + 1] : (f16)0.0f;
    }

    // ---- phase 2a: per-pixel plane selection (exact: count coc > bnd[k]) ----
    {
        const int row = tid >> 3;
        const int x4  = (tid & 7) * 4;
        const float4 c4 = *(const float4*)&coc_map[((size_t)bb * HH + by * TH + row) * WW + bx * TW + x4];
        const float cv[4] = {c4.x, c4.y, c4.z, c4.w};
        int pp[4] = {0, 0, 0, 0};
        #pragma unroll
        for (int k = 0; k < KW; ++k) {
            const float b = bnd[k];
            pp[0] += (cv[0] > b) ? 1 : 0;
            pp[1] += (cv[1] > b) ? 1 : 0;
            pp[2] += (cv[2] > b) ? 1 : 0;
            pp[3] += (cv[3] > b) ? 1 : 0;
        }
        *(uchar4*)&pl8[row][x4] = make_uchar4((unsigned char)pp[0], (unsigned char)pp[1],
                                              (unsigned char)pp[2], (unsigned char)pp[3]);
    }

    // ---- phase 2b: stage tile (+halo) as f16, zero all padding ----
    for (int idx = tid; idx < 3 * EXT_Y * (SX / 2); idx += 256) {
        const int dw = idx % (SX / 2);
        const int rr = (idx / (SX / 2)) % EXT_Y;
        const int ch = idx / ((SX / 2) * EXT_Y);
        const int gy  = by * TH - R + rr;
        const int gxa = bx * TW - R + 2 * dw;
        float va = 0.0f, vb = 0.0f;
        if (rr < 62 && (unsigned)gy < HH) {
            const float* src = &sharp[(((size_t)bb * 3 + ch) * HH + gy) * WW];
            if (2 * dw + 1 < EXT_X && (unsigned)gxa < WW && (unsigned)(gxa + 1) < WW) {
                const float2 v2 = *(const float2*)&src[gxa];   // interior: one dwordx2
                va = v2.x; vb = v2.y;
            } else {
                if (2 * dw     < EXT_X && (unsigned)gxa       < WW) va = src[gxa];
                if (2 * dw + 1 < EXT_X && (unsigned)(gxa + 1) < WW) vb = src[gxa + 1];
            }
        }
        f16x2 h; h.x = (f16)va; h.y = (f16)vb;
        *(f16x2*)&tile[ch][rr][2 * dw] = h;
    }
    __syncthreads();

    // ---- phase 3: one 32x32 GEMM (K=64) per (row, channel) ----
    // S[dy][px] = sum_k tile[r+dy][k] * g_{plane(px)}[k - px]   (tap = k-px, zero-padded)
    // A: m=lane&31 (dy), k=(lane>>5)*8+j (+16kc). C/D: col=lane&31 (px),
    // row=(reg&3)+8(reg>>2)+4(lane>>5) (dy). Partials split only across h=lane>>5.
    const int lid = tid & 63, wv = tid >> 6;
    const int c32 = lid & 31, h = lid >> 5;
    const int cp = c32 & 1;                       // parity copy (window parity == px parity)
    const int dwb0 = (GB + 8 * h - c32) >> 1;     // chunk-0 start dword within copy; in [0,20]

    union U8 { f16x2 h2[4]; f16x8 h8; };

    #pragma unroll 4
    for (int r = wv; r < TH; r += 4) {            // 32 tasks: one per row
        const int pm = pl8[r][c32];
        const f16* tab = &gTh2[pm][cp][0];

        // B-frags: chunk kc covers k=16kc+8h+j; f16 idx o = GB + k - c32
        U8 bf[4];
        #pragma unroll
        for (int kc = 0; kc < 4; ++kc)
            #pragma unroll
            for (int n = 0; n < 4; ++n)
                bf[kc].h2[n] = *(const f16x2*)&tab[2 * (dwb0 + 8 * kc + n)];

        // y-weights: dy = 8a + 4h + b  -> 4 aligned f16x4 (b64) reads
        f16x4 wy[4];
        #pragma unroll
        for (int a = 0; a < 4; ++a)
            wy[a] = *(const f16x4*)&gTh2[pm][0][GB + 8 * a + 4 * h];

        float o[3];
        #pragma unroll
        for (int ch = 0; ch < 3; ++ch) {
            const f16* ap = &tile[ch][r + c32][8 * h];
            f32x16 acc;
            #pragma unroll
            for (int i = 0; i < 16; ++i) acc[i] = 0.0f;
            acc = __builtin_amdgcn_mfma_f32_32x32x16_f16(*(const f16x8*)(ap     ), bf[0].h8, acc, 0, 0, 0);
            acc = __builtin_amdgcn_mfma_f32_32x32x16_f16(*(const f16x8*)(ap + 16), bf[1].h8, acc, 0, 0, 0);
            acc = __builtin_amdgcn_mfma_f32_32x32x16_f16(*(const f16x8*)(ap + 32), bf[2].h8, acc, 0, 0, 0);
            acc = __builtin_amdgcn_mfma_f32_32x32x16_f16(*(const f16x8*)(ap + 48), bf[3].h8, acc, 0, 0, 0);
            float s = 0.0f;
            #pragma unroll
            for (int a = 0; a < 4; ++a)
                #pragma unroll
                for (int b = 0; b < 4; ++b)
                    s = fmaf((float)wy[a][b], acc[4 * a + b], s);
            o[ch] = s;
        }

        // other dy-half lives at lane ^ 32
        #pragma unroll
        for (int ch = 0; ch < 3; ++ch) o[ch] += __shfl_xor(o[ch], 32, 64);

        if (h == 0) {
            const int oy = by * TH + r;
            const int ox = bx * TW + c32;
            #pragma unroll
            for (int ch = 0; ch < 3; ++ch)
                out[(((size_t)bb * 3 + ch) * HH + oy) * WW + ox] = o[ch];
        }
    }
}

extern "C" void kernel_launch(void* const* d_in, const int* in_sizes, int n_in,
                              void* d_out, int out_size, void* d_ws, size_t ws_size,
                              hipStream_t stream) {
    const float* sharp = (const float*)d_in[0];
    const float* coc   = (const float*)d_in[1];
    float* outp        = (float*)d_out;
    dim3 grid(WW / TW, HH / TH, NB);
    defocus_kernel<<<grid, dim3(256), 0, stream>>>(sharp, coc, outp);
}